// Round 12
// baseline (393.965 us; speedup 1.0000x reference)
//
#include <hip/hip_runtime.h>
#include <math.h>

#define B_   16
#define C_   1536
#define N_   1024
#define M_   64
#define L_   128
#define G_   256
#define HID_ 512

typedef __attribute__((ext_vector_type(8))) short short8;
typedef __attribute__((ext_vector_type(4))) float floatx4;

// round-to-nearest-even fp32 -> bf16
__device__ __forceinline__ unsigned short f2bf_rne(float x) {
    unsigned u = __float_as_uint(x);
    unsigned r = u + 0x7fffu + ((u >> 16) & 1u);
    return (unsigned short)(r >> 16);
}
// round-half-up packed pair (cheap, hot path)
__device__ __forceinline__ unsigned pack_bf2(float lo, float hi) {
    unsigned a = __float_as_uint(lo) + 0x8000u;
    unsigned b = __float_as_uint(hi) + 0x8000u;
    return (a >> 16) | (b & 0xffff0000u);
}

__device__ __forceinline__ void gl2lds16(const void* g, void* l) {
    __builtin_amdgcn_global_load_lds(
        (const __attribute__((address_space(1))) void*)g,
        (__attribute__((address_space(3))) void*)l, 16, 0, 0);
}

// ---------------------------------------------------------------------------
// Weight cast: Wbf[1024][1536] = stack(Wc1,Ws1) bf16 (float4 path);
// W2[192][1024] = [Wc2 | 0 ; 0 | Ws2] bf16.
// ---------------------------------------------------------------------------
__global__ __launch_bounds__(256) void cast_w_kernel(
    const float* __restrict__ Wc1, const float* __restrict__ Ws1,
    const float* __restrict__ Wc2, const float* __restrict__ Ws2,
    unsigned short* __restrict__ Wbf, unsigned short* __restrict__ W2)
{
    const int V1 = 393216;           // (1024*1536)/4 float4s
    const int VH = 196608;           // Wc1 half in float4s
    int idx = blockIdx.x * 256 + threadIdx.x;
    if (idx < V1) {
        const float4* src = (idx < VH) ? (const float4*)Wc1 : (const float4*)Ws1;
        float4 v = src[(idx < VH) ? idx : idx - VH];
        ushort4 o;
        o.x = f2bf_rne(v.x); o.y = f2bf_rne(v.y);
        o.z = f2bf_rne(v.z); o.w = f2bf_rne(v.w);
        ((ushort4*)Wbf)[idx] = o;
    } else if (idx < V1 + 192 * 1024) {
        int i2 = idx - V1;
        int row = i2 >> 10, k = i2 & 1023;
        float v = 0.f;
        if (row < 128) { if (k < 512) v = Wc2[row * 512 + k]; }
        else           { if (k >= 512) v = Ws2[(row - 128) * 512 + (k - 512)]; }
        W2[i2] = f2bf_rne(v);
    }
}

// ---------------------------------------------------------------------------
// Transpose+cast: xT[b][n][c] bf16 <- x[b][c][n] fp32. 64x64 LDS tile.
// float4 global loads (16B/lane), uint2 global stores (8B/lane).
// ---------------------------------------------------------------------------
__global__ __launch_bounds__(256) void xt_kernel(
    const float* __restrict__ x, unsigned short* __restrict__ xT)
{
    __shared__ float Xs[64][65];
    const int t = threadIdx.x;
    const int n0 = blockIdx.x * 64, c0 = blockIdx.y * 64, b = blockIdx.z;
    const float* xb = x + (long)b * C_ * N_;
    #pragma unroll
    for (int it = 0; it < 4; ++it) {
        int idx = it * 256 + t, cr = idx >> 4, fc = idx & 15;
        float4 v = *(const float4*)&xb[(long)(c0 + cr) * N_ + n0 + fc * 4];
        Xs[cr][fc * 4 + 0] = v.x;
        Xs[cr][fc * 4 + 1] = v.y;
        Xs[cr][fc * 4 + 2] = v.z;
        Xs[cr][fc * 4 + 3] = v.w;
    }
    __syncthreads();
    uint2* xo = (uint2*)(xT + (long)b * N_ * C_);
    #pragma unroll
    for (int it = 0; it < 4; ++it) {
        int idx = it * 256 + t, nr = idx >> 4, pc = idx & 15;
        uint2 o;
        o.x = pack_bf2(Xs[4 * pc + 0][nr], Xs[4 * pc + 1][nr]);
        o.y = pack_bf2(Xs[4 * pc + 2][nr], Xs[4 * pc + 3][nr]);
        xo[(long)(n0 + nr) * 384 + (c0 >> 2) + pc] = o;
    }
}

// ---------------------------------------------------------------------------
// GEMM1 — 256x256-tile 8-phase deep-pipelined bf16 MFMA (m201/HK schedule).
// Epilogue: LDS-transposed coalesced C-write (16B contiguous segments).
// ---------------------------------------------------------------------------
#define G1_STAGE_A(kt, q)                                                    \
    gl2lds16(aSrc + (long)(q) * (32 * C_) + (kt) * 64,                       \
             (char*)g1lds + (((kt) & 1) * 65536 + (q) * 8192) + sdst)
#define G1_STAGE_B(kt, q)                                                    \
    gl2lds16(bSrc + (long)(q) * (32 * C_) + (kt) * 64,                       \
             (char*)g1lds + (((kt) & 1) * 65536 + 32768 + (q) * 8192) + sdst)

#define G1_PHASE(q, STAGES, TAIL)                                            \
  {                                                                          \
    const char* ab = cb + aFB + (q) * 8192;                                  \
    short8 a0 = *(const short8*)(ab + ks0);                                  \
    short8 a1 = *(const short8*)(ab + ks1);                                  \
    short8 a2 = *(const short8*)(ab + 2048 + ks0);                           \
    short8 a3 = *(const short8*)(ab + 2048 + ks1);                           \
    STAGES                                                                   \
    __builtin_amdgcn_s_barrier();                                            \
    asm volatile("s_waitcnt lgkmcnt(0)" ::: "memory");                       \
    __builtin_amdgcn_sched_barrier(0);                                       \
    __builtin_amdgcn_s_setprio(1);                                           \
    _Pragma("unroll")                                                        \
    for (int fj = 0; fj < 4; ++fj) {                                         \
      acc[2*(q)][fj]   = __builtin_amdgcn_mfma_f32_16x16x32_bf16(            \
          a0, bfr[fj][0], acc[2*(q)][fj], 0, 0, 0);                          \
      acc[2*(q)][fj]   = __builtin_amdgcn_mfma_f32_16x16x32_bf16(            \
          a1, bfr[fj][1], acc[2*(q)][fj], 0, 0, 0);                          \
      acc[2*(q)+1][fj] = __builtin_amdgcn_mfma_f32_16x16x32_bf16(            \
          a2, bfr[fj][0], acc[2*(q)+1][fj], 0, 0, 0);                        \
      acc[2*(q)+1][fj] = __builtin_amdgcn_mfma_f32_16x16x32_bf16(            \
          a3, bfr[fj][1], acc[2*(q)+1][fj], 0, 0, 0);                        \
    }                                                                        \
    __builtin_amdgcn_s_setprio(0);                                           \
    TAIL                                                                     \
    __builtin_amdgcn_s_barrier();                                            \
    __builtin_amdgcn_sched_barrier(0);                                       \
  }

#define G1_TILE(tt, S1, S2, TAIL3)                                           \
  {                                                                          \
    const char* cb = (const char*)g1lds + ((tt) & 1) * 65536;                \
    _Pragma("unroll")                                                        \
    for (int fj = 0; fj < 4; ++fj) {                                         \
      const char* bb = cb + bFB + (fj >> 1) * 8192 + (fj & 1) * 2048;        \
      bfr[fj][0] = *(const short8*)(bb + ks0);                               \
      bfr[fj][1] = *(const short8*)(bb + ks1);                               \
    }                                                                        \
    G1_PHASE(0, if (S1) { G1_STAGE_A((tt)+1, 2); G1_STAGE_A((tt)+1, 3); }, ) \
    G1_PHASE(1, if (S2) { G1_STAGE_B((tt)+2, 0); G1_STAGE_B((tt)+2, 1); }, ) \
    G1_PHASE(2, if (S2) { G1_STAGE_B((tt)+2, 2); G1_STAGE_B((tt)+2, 3); }, ) \
    G1_PHASE(3, if (S2) { G1_STAGE_A((tt)+2, 0); G1_STAGE_A((tt)+2, 1); }, TAIL3) \
  }

__global__ __launch_bounds__(512, 2) void gemm1_kernel(
    const unsigned short* __restrict__ Wbf, const unsigned short* __restrict__ xT,
    const float* __restrict__ bc1, const float* __restrict__ bs1,
    unsigned short* __restrict__ hT)
{
    __shared__ unsigned short g1lds[65536];   // 128 KiB
    const int t = threadIdx.x;
    const int lane = t & 63, w = t >> 6;
    const int n0 = blockIdx.x * 256, o0 = blockIdx.y * 256, b = blockIdx.z;

    const int sgrow = ((t & 256) ? 128 : 0) + ((t >> 3) & 31);
    const int sdst  = t * 16;
    const int sslot = ((t & 7) ^ ((t >> 3) & 7)) * 8;
    const unsigned short* aSrc = Wbf + (long)(o0 + sgrow) * C_ + sslot;
    const unsigned short* bSrc = xT + (long)b * N_ * C_
                               + (long)(n0 + sgrow) * C_ + sslot;

    const int lrow = lane & 15, kgrp = lane >> 4;
    const int wo = (w >> 2) * 128, wn = (w & 3) * 64;
    const int aFB = (w >> 2) * 4096 + lrow * 128;
    const int bFB = 32768 + ((w >> 1) & 1) * 4096 + (w & 1) * 16384 + lrow * 128;
    const int ks0 = (kgrp ^ (lrow & 7)) * 16;
    const int ks1 = ((4 + kgrp) ^ (lrow & 7)) * 16;

    floatx4 acc[8][4];
    #pragma unroll
    for (int i = 0; i < 8; ++i)
        #pragma unroll
        for (int j = 0; j < 4; ++j) acc[i][j] = (floatx4)0.0f;
    short8 bfr[4][2];

    #pragma unroll
    for (int q = 0; q < 4; ++q) { G1_STAGE_A(0, q); G1_STAGE_B(0, q); }
    #pragma unroll
    for (int q = 0; q < 4; ++q) G1_STAGE_B(1, q);
    G1_STAGE_A(1, 0); G1_STAGE_A(1, 1);
    asm volatile("s_waitcnt vmcnt(6)" ::: "memory");
    __builtin_amdgcn_s_barrier();
    __builtin_amdgcn_sched_barrier(0);

    #pragma unroll 2
    for (int t8 = 0; t8 < 22; ++t8)
        G1_TILE(t8, 1, 1, asm volatile("s_waitcnt vmcnt(6)" ::: "memory");)
    G1_TILE(22, 1, 0, asm volatile("s_waitcnt vmcnt(0)" ::: "memory");)
    G1_TILE(23, 0, 0, )

    // ---- epilogue: bias+relu+pack into LDS [n 256][o 256] bf16 (512B rows,
    // XOR-swizzled 16B slots), then fully-coalesced 16B copy-out. ----
    const float* bias = (o0 < 512) ? bc1 : bs1;
    const int ob = (o0 < 512) ? o0 : o0 - 512;
    #pragma unroll
    for (int fi = 0; fi < 8; ++fi) {
        const int orow = wo + fi * 16 + kgrp * 4;
        float4 bv = *(const float4*)&bias[ob + orow];
        #pragma unroll
        for (int fj = 0; fj < 4; ++fj) {
            const int nl = wn + fj * 16 + lrow;
            float v0 = fmaxf(acc[fi][fj][0] + bv.x, 0.f);
            float v1 = fmaxf(acc[fi][fj][1] + bv.y, 0.f);
            float v2 = fmaxf(acc[fi][fj][2] + bv.z, 0.f);
            float v3 = fmaxf(acc[fi][fj][3] + bv.w, 0.f);
            uint2 pk;
            pk.x = ((unsigned)f2bf_rne(v0)) | (((unsigned)f2bf_rne(v1)) << 16);
            pk.y = ((unsigned)f2bf_rne(v2)) | (((unsigned)f2bf_rne(v3)) << 16);
            *(uint2*)((char*)g1lds + nl * 512 + ((orow * 2) ^ ((nl & 7) << 4))) = pk;
        }
    }
    __syncthreads();
    {
        uint4* dst = (uint4*)(hT + ((long)b * N_ + n0) * 1024 + o0);
        #pragma unroll
        for (int it = 0; it < 16; ++it) {
            int c = it * 512 + t;            // 8192 16B chunks
            int nl = c >> 5, k = c & 31;
            uint4 v = *(const uint4*)((const char*)g1lds +
                          nl * 512 + ((k * 16) ^ ((nl & 7) << 4)));
            dst[(long)nl * 128 + k] = v;
        }
    }
}

// ---------------------------------------------------------------------------
// GEMM23 (bf16 MFMA): o-blocks 0,1 -> f fp32; o-block 2 -> K = exp(p) fp32
// PLUS deterministic per-(b,nx) partial row sums part[b][nx][64].
// W2 block-diagonal: each o-block runs only its live 512-wide K range.
// ---------------------------------------------------------------------------
__global__ __launch_bounds__(256, 2) void gemm23_kernel(
    const unsigned short* __restrict__ W2, const unsigned short* __restrict__ hT,
    const float* __restrict__ bc2, const float* __restrict__ bs2,
    float* __restrict__ f, float* __restrict__ p, float* __restrict__ part)
{
    __shared__ unsigned short As[64 * 32];
    __shared__ unsigned short Bs[128 * 32];
    __shared__ float prs[M_][2];
    const int t = threadIdx.x;
    const int lane = t & 63, w = t >> 6;
    const int n0 = blockIdx.x * 128, o0 = blockIdx.y * 64, b = blockIdx.z;
    const unsigned short* hTb = hT + (long)b * N_ * 1024;

    const int wo = (w >> 1) * 32, wn = (w & 1) * 64;
    const int lrow = lane & 15, kgrp = lane >> 4;
    const int arow = t >> 2, acol = (t & 3) * 8;
    const int klo = (o0 < 128) ? 0 : 512;   // live K half for this o-block

    floatx4 acc[2][4];
    #pragma unroll
    for (int i = 0; i < 2; ++i)
        #pragma unroll
        for (int j = 0; j < 4; ++j) acc[i][j] = (floatx4)0.0f;

    for (int k0 = 0; k0 < 512; k0 += 32) {
        gl2lds16(W2 + (long)(o0 + arow) * 1024 + klo + k0 + acol, (char*)As + t * 16);
        #pragma unroll
        for (int r = 0; r < 2; ++r)
            gl2lds16(hTb + (long)(n0 + r * 64 + arow) * 1024 + klo + k0 + acol,
                     (char*)Bs + r * 4096 + t * 16);
        __syncthreads();
        short8 af[2], bfr[4];
        #pragma unroll
        for (int i = 0; i < 2; ++i)
            af[i] = *(const short8*)((const char*)As +
                        (wo + i * 16 + lrow) * 64 + kgrp * 16);
        #pragma unroll
        for (int j = 0; j < 4; ++j)
            bfr[j] = *(const short8*)((const char*)Bs +
                        (wn + j * 16 + lrow) * 64 + kgrp * 16);
        #pragma unroll
        for (int i = 0; i < 2; ++i)
            #pragma unroll
            for (int j = 0; j < 4; ++j)
                acc[i][j] = __builtin_amdgcn_mfma_f32_16x16x32_bf16(
                    af[i], bfr[j], acc[i][j], 0, 0, 0);
        __syncthreads();
    }

    if (o0 < 128) {
        #pragma unroll
        for (int i = 0; i < 2; ++i) {
            int o = o0 + wo + i * 16 + kgrp * 4;
            #pragma unroll
            for (int j = 0; j < 4; ++j) {
                int n = n0 + wn + j * 16 + lrow;
                #pragma unroll
                for (int r = 0; r < 4; ++r)
                    f[((long)b * L_ + o + r) * N_ + n] = acc[i][j][r] + bc2[o + r];
            }
        }
    } else {
        float pir[2][4];
        #pragma unroll
        for (int i = 0; i < 2; ++i) {
            const int m = wo + i * 16 + kgrp * 4;   // row within [0,64)
            #pragma unroll
            for (int r = 0; r < 4; ++r) pir[i][r] = 0.f;
            #pragma unroll
            for (int j = 0; j < 4; ++j) {
                int n = n0 + wn + j * 16 + lrow;
                #pragma unroll
                for (int r = 0; r < 4; ++r) {
                    float K = expf(acc[i][j][r] + bs2[m + r]);
                    p[((long)b * M_ + m + r) * N_ + n] = K;
                    pir[i][r] += K;
                }
            }
            #pragma unroll
            for (int r = 0; r < 4; ++r) {
                float s = pir[i][r];
                s += __shfl_xor(s, 1); s += __shfl_xor(s, 2);
                s += __shfl_xor(s, 4); s += __shfl_xor(s, 8);
                if (lrow == 0) prs[m + r][w & 1] = s;
            }
        }
        __syncthreads();
        if (t < M_)
            part[((long)b * 8 + blockIdx.x) * M_ + t] = prs[t][0] + prs[t][1];
    }
}

// ---------------------------------------------------------------------------
// Token head: wave-per-output GEMV kernels (split; wide grids)
// ---------------------------------------------------------------------------
__global__ __launch_bounds__(256) void token1_kernel(
    const float* __restrict__ t_in, const float* __restrict__ Wt1,
    const float* __restrict__ bt1, float* __restrict__ hid)
{
    const int lane = threadIdx.x & 63, w = threadIdx.x >> 6;
    const int o = blockIdx.x * 4 + w, b = blockIdx.y;
    const float4* wr = (const float4*)(Wt1 + (long)o * C_);
    const float4* tb = (const float4*)(t_in + (long)b * C_);
    float acc = 0.f;
    #pragma unroll
    for (int i = 0; i < 6; ++i) {
        float4 a = wr[i * 64 + lane], tv = tb[i * 64 + lane];
        acc += a.x * tv.x + a.y * tv.y + a.z * tv.z + a.w * tv.w;
    }
    #pragma unroll
    for (int off = 1; off < 64; off <<= 1) acc += __shfl_xor(acc, off);
    if (lane == 0) hid[b * HID_ + o] = fmaxf(acc + bt1[o], 0.f);
}

__global__ __launch_bounds__(256) void token2_kernel(
    const float* __restrict__ hid, const float* __restrict__ Wt2,
    const float* __restrict__ bt2, float* __restrict__ tok)
{
    const int lane = threadIdx.x & 63, w = threadIdx.x >> 6;
    const int g = blockIdx.x * 4 + w, b = blockIdx.y;
    const float4* wr = (const float4*)(Wt2 + (long)g * HID_);
    const float4* hb = (const float4*)(hid + (long)b * HID_);
    float acc = 0.f;
    #pragma unroll
    for (int i = 0; i < 2; ++i) {
        float4 a = wr[i * 64 + lane], hv = hb[i * 64 + lane];
        acc += a.x * hv.x + a.y * hv.y + a.z * hv.z + a.w * hv.w;
    }
    #pragma unroll
    for (int off = 1; off < 64; off <<= 1) acc += __shfl_xor(acc, off);
    if (lane == 0) tok[b * G_ + g] = acc + bt2[g];
}

__global__ __launch_bounds__(256) void token3_kernel(
    const float* __restrict__ tok, float* __restrict__ tokn)
{
    __shared__ float red[4];
    const int b = blockIdx.x, t = threadIdx.x;
    float v = tok[b * G_ + t];
    float ss = v * v;
    #pragma unroll
    for (int off = 1; off < 64; off <<= 1) ss += __shfl_xor(ss, off);
    if ((t & 63) == 0) red[t >> 6] = ss;
    __syncthreads();
    float inv = 1.f / fmaxf(sqrtf(red[0] + red[1] + red[2] + red[3]), 1e-12f);
    tokn[b * G_ + t] = v * inv;
}

// ---------------------------------------------------------------------------
// Fused kv+ku pass: each block redundantly computes the full bvec for its
// batch into LDS, then its own row-dots. FIRST variant builds the initial
// a-vector from gemm23's partial row sums (u1) before kv1+ku2.
// ---------------------------------------------------------------------------
template<bool FIRST>
__global__ __launch_bounds__(256) void kvku_kernel(
    const float* __restrict__ K, const float* __restrict__ dust,
    const float* __restrict__ ain, float* __restrict__ avec_out)
{
    __shared__ float a_s[M_ + 1];
    __shared__ float b_lds[N_];
    const int t = threadIdx.x, lane = t & 63, w = t >> 6;
    const int mg = blockIdx.x, b = blockIdx.y;
    const float ea = expf(dust[0]);
    const float* Kb = K + (long)b * M_ * N_;

    if (FIRST) {
        if (t < M_) {
            float s = 0.f;
            #pragma unroll
            for (int nx = 0; nx < 8; ++nx) s += ain[((long)b * 8 + nx) * M_ + t];
            a_s[t] = (1.f / 1088.f) / s;
        } else if (t == M_) {
            a_s[M_] = (1024.f / 1088.f) / (1024.f * ea);
        }
    } else {
        if (t < M_ + 1) a_s[t] = ain[b * (M_ + 1) + t];
    }
    __syncthreads();

    // kv phase, 4 cols/thread
    #pragma unroll
    for (int k = 0; k < 4; ++k) {
        int n = k * 256 + t;
        float s = ea * a_s[M_];
        const float* col = Kb + n;
        #pragma unroll
        for (int m = 0; m < M_; ++m) s = fmaf(col[(long)m * N_], a_s[m], s);
        b_lds[n] = (1.f / 1088.f) / s;
    }
    __syncthreads();

    // ku phase
    const int m = mg * 4 + w;
    if (m > M_) return;
    float s = 0.f;
    if (m < M_) {
        const float* row = Kb + (long)m * N_;
        #pragma unroll
        for (int i = 0; i < 16; ++i) {
            int n = i * 64 + lane;
            s = fmaf(row[n], b_lds[n], s);
        }
    } else {
        #pragma unroll
        for (int i = 0; i < 16; ++i) s += b_lds[i * 64 + lane];
        s *= ea;
    }
    #pragma unroll
    for (int off = 1; off < 64; off <<= 1) s += __shfl_xor(s, off);
    if (lane == 0) {
        float mu = (m < M_) ? (1.f / 1088.f) : (1024.f / 1088.f);
        avec_out[b * (M_ + 1) + m] = mu / s;
    }
}

// ---------------------------------------------------------------------------
// tnorm: computes T, zeroes draw, writes fnT[b][n][128] bf16.
// ---------------------------------------------------------------------------
__global__ __launch_bounds__(256) void tnorm_kernel(
    const float* __restrict__ f, const float* __restrict__ Wtp,
    const float* __restrict__ btp, unsigned short* __restrict__ fnT,
    float* __restrict__ T, float* __restrict__ draw)
{
    __shared__ float Ft[L_][65];
    __shared__ float red_ss[4][64];
    __shared__ float red_dot[4][64];
    __shared__ float invs[64];
    __shared__ float wtp_s[L_];
    const int b = blockIdx.y, n0 = blockIdx.x * 64, t = threadIdx.x;
    const float* fb = f + (long)b * L_ * N_;

    if (t < L_) wtp_s[t] = Wtp[t];
    for (int it = 0; it < 32; ++it) {
        int idx = it * 256 + t;
        int l = idx >> 6, c = idx & 63;
        Ft[l][c] = fb[(long)l * N_ + n0 + c];
    }
    __syncthreads();
    {
        const int lg = t >> 6, col = t & 63;
        float ss = 0.f, dot = 0.f;
        #pragma unroll
        for (int i = 0; i < 32; ++i) {
            int l = lg * 32 + i;
            float v = Ft[l][col];
            ss = fmaf(v, v, ss);
            dot = fmaf(v, wtp_s[l], dot);
        }
        red_ss[lg][col] = ss;
        red_dot[lg][col] = dot;
    }
    __syncthreads();
    if (t < 64) {
        float ss = ((red_ss[0][t] + red_ss[1][t]) + (red_ss[2][t] + red_ss[3][t]));
        float dot = ((red_dot[0][t] + red_dot[1][t]) + (red_dot[2][t] + red_dot[3][t]));
        invs[t] = 1.f / fmaxf(sqrtf(ss), 1e-12f);
        float xx = dot + btp[0];
        T[b * N_ + n0 + t] = (xx > 0.f) ? (xx + log1pf(expf(-xx)))
                                        : log1pf(expf(xx));
        draw[b * N_ + n0 + t] = 0.f;
    }
    __syncthreads();
    unsigned* fo = (unsigned*)fnT;
    for (int it = 0; it < 16; ++it) {
        int idx = it * 256 + t;
        int nl = idx >> 6, jp = idx & 63;
        float inv = invs[nl];
        fo[(((long)b * N_ + n0 + nl) << 6) + jp] =
            pack_bf2(Ft[2 * jp][nl] * inv, Ft[2 * jp + 1][nl] * inv);
    }
}

// ---------------------------------------------------------------------------
// sim (bf16 MFMA): draw[b][i] += sum_j sigmoid(0.5*(Ti+Tj)*(fn_i . fn_j) + bb)
// ---------------------------------------------------------------------------
__global__ __launch_bounds__(256) void sim_kernel(
    const unsigned short* __restrict__ fnT, const float* __restrict__ T,
    const float* __restrict__ bb, float* __restrict__ draw)
{
    __shared__ unsigned short As[64 * 136];
    __shared__ unsigned short Bs[64 * 136];
    __shared__ float Ti[64], Tj[64];
    const int b = blockIdx.z, i0 = blockIdx.y * 64, j0base = blockIdx.x * 256;
    const int t = threadIdx.x, lane = t & 63, w = t >> 6;
    const int lrow = lane & 15, kgrp = lane >> 4;
    const unsigned short* fb = fnT + (long)b * N_ * 128;
    const float burstb = bb[0];

    if (t < 64) Ti[t] = T[b * N_ + i0 + t];
    const int srow = t >> 4, scol = (t & 15) * 8;
    #pragma unroll
    for (int r = 0; r < 4; ++r) {
        uint4 av = *(const uint4*)(fb + (long)(i0 + r * 16 + srow) * 128 + scol);
        *(uint4*)((char*)As + (r * 16 + srow) * 272 + scol * 2) = av;
    }
    uint4 bv[4];
    #pragma unroll
    for (int r = 0; r < 4; ++r)
        bv[r] = *(const uint4*)(fb + (long)(j0base + r * 16 + srow) * 128 + scol);

    float rs[4] = {0.f, 0.f, 0.f, 0.f};
    #pragma unroll
    for (int jj = 0; jj < 4; ++jj) {
        __syncthreads();
        #pragma unroll
        for (int r = 0; r < 4; ++r)
            *(uint4*)((char*)Bs + (r * 16 + srow) * 272 + scol * 2) = bv[r];
        if (t >= 64 && t < 128) Tj[t - 64] = T[b * N_ + j0base + jj * 64 + (t - 64)];
        if (jj < 3) {
            #pragma unroll
            for (int r = 0; r < 4; ++r)
                bv[r] = *(const uint4*)(fb +
                    (long)(j0base + (jj + 1) * 64 + r * 16 + srow) * 128 + scol);
        }
        __syncthreads();

        floatx4 acc[4];
        #pragma unroll
        for (int j = 0; j < 4; ++j) acc[j] = (floatx4)0.0f;
        __builtin_amdgcn_s_setprio(1);
        #pragma unroll
        for (int k0 = 0; k0 < 128; k0 += 32) {
            short8 af = *(const short8*)((const char*)As +
                            (w * 16 + lrow) * 272 + k0 * 2 + kgrp * 16);
            #pragma unroll
            for (int j = 0; j < 4; ++j) {
                short8 bf = *(const short8*)((const char*)Bs +
                                (j * 16 + lrow) * 272 + k0 * 2 + kgrp * 16);
                acc[j] = __builtin_amdgcn_mfma_f32_16x16x32_bf16(af, bf, acc[j], 0, 0, 0);
            }
        }
        __builtin_amdgcn_s_setprio(0);
        #pragma unroll
        for (int j = 0; j < 4; ++j) {
            float Tjv = Tj[j * 16 + lrow];
            #pragma unroll
            for (int r = 0; r < 4; ++r) {
                float Tiv = Ti[w * 16 + kgrp * 4 + r];
                float xarg = 0.5f * (Tiv + Tjv) * acc[j][r] + burstb;
                rs[r] += 1.f / (1.f + expf(-xarg));
            }
        }
    }

    #pragma unroll
    for (int off = 1; off < 16; off <<= 1)
        #pragma unroll
        for (int r = 0; r < 4; ++r) rs[r] += __shfl_xor(rs[r], off);
    if (lrow == 0) {
        #pragma unroll
        for (int r = 0; r < 4; ++r)
            atomicAdd(&draw[b * N_ + i0 + w * 16 + kgrp * 4 + r], rs[r]);
    }
}

// ---------------------------------------------------------------------------
// agg (+ fused final kv + inlined wn): Pch[m][c] = K[m][n0+c]*a[m];
// s_c = sum_m Pch + dust; cf[c] = wn(draw[c])/s_c. ATOMIC-FREE: block
// (nb,b) writes its private L x M slice to aggp[b][nb][L*M].
// ---------------------------------------------------------------------------
__global__ __launch_bounds__(256) void agg_kernel(
    const float* __restrict__ f, const float* __restrict__ Kmat,
    const float* __restrict__ avec, const float* __restrict__ dust,
    const float* __restrict__ draw, const float* __restrict__ bp,
    const float* __restrict__ lamd, float* __restrict__ aggp)
{
    __shared__ float fch[L_][65];
    __shared__ float Pch[M_][65];
    __shared__ float a_s[M_ + 1], cf[64];
    const int b = blockIdx.y, nb = blockIdx.x, n0 = nb * 64;
    const int t = threadIdx.x, tx = t & 15, ty = t >> 4;
    const float* fb = f + (long)b * L_ * N_;
    const float* Kb = Kmat + (long)b * M_ * N_;

    if (t < M_ + 1) a_s[t] = avec[b * (M_ + 1) + t];
    __syncthreads();

    for (int idx = t; idx < L_ * 64; idx += 256) {
        int l = idx >> 6, c = idx & 63;
        fch[l][c] = fb[(long)l * N_ + n0 + c];
    }
    for (int idx = t; idx < M_ * 64; idx += 256) {
        int m = idx >> 6, c = idx & 63;
        Pch[m][c] = Kb[(long)m * N_ + n0 + c] * a_s[m];
    }
    __syncthreads();

    if (t < 64) {
        float s = expf(dust[0]) * a_s[M_];
        #pragma unroll
        for (int m = 0; m < M_; ++m) s += Pch[m][t];
        float d = powf(draw[b * N_ + n0 + t], bp[0]);
        d = fminf(fmaxf(d, 1e-3f), 1e3f);
        float lam = 1.f / (1.f + expf(-lamd[0]));
        cf[t] = ((1.f - lam) + lam / (d + 1e-6f)) / s;
    }
    __syncthreads();

    float acc[8][4] = {};
    for (int n = 0; n < 64; ++n) {
        float cfn = cf[n];
        float fv[8], pv[4];
        #pragma unroll
        for (int i = 0; i < 8; ++i) fv[i] = fch[ty + 16 * i][n];
        #pragma unroll
        for (int j = 0; j < 4; ++j) pv[j] = Pch[tx * 4 + j][n] * cfn;
        #pragma unroll
        for (int i = 0; i < 8; ++i)
            #pragma unroll
            for (int j = 0; j < 4; ++j)
                acc[i][j] = fmaf(fv[i], pv[j], acc[i][j]);
    }
    float* op = aggp + ((long)b * 16 + nb) * (L_ * M_);
    #pragma unroll
    for (int i = 0; i < 8; ++i) {
        float4 v = make_float4(acc[i][0], acc[i][1], acc[i][2], acc[i][3]);
        *(float4*)&op[(ty + 16 * i) * M_ + tx * 4] = v;
    }
}

// ---------------------------------------------------------------------------
// final: reduce 16 agg slices -> LDS, per-cluster l2norm over L,
// concat [tok_n, agg_n], global l2norm.
// ---------------------------------------------------------------------------
__global__ __launch_bounds__(256) void final_kernel(
    const float* __restrict__ tokn, const float* __restrict__ aggp,
    float* __restrict__ out)
{
    __shared__ float ar[L_ * M_];    // 32 KiB
    __shared__ float invm[M_];
    __shared__ float red[4];
    __shared__ float s_invtot;
    const int b = blockIdx.x, t = threadIdx.x;
    const float* pb = aggp + (long)b * 16 * (L_ * M_);

    for (int idx = t; idx < L_ * M_; idx += 256) {
        float s = 0.f;
        #pragma unroll
        for (int nb = 0; nb < 16; ++nb) s += pb[nb * (L_ * M_) + idx];
        ar[idx] = s;
    }
    __syncthreads();

    if (t < 64) {
        float ss = 0.f;
        for (int l = 0; l < L_; ++l) {
            float v = ar[l * M_ + t];
            ss = fmaf(v, v, ss);
        }
        invm[t] = 1.f / fmaxf(sqrtf(ss), 1e-12f);
    }
    __syncthreads();

    float part;
    {
        float tn = tokn[b * G_ + t];
        part = tn * tn;
    }
    for (int idx = t; idx < L_ * M_; idx += 256) {
        float v = ar[idx] * invm[idx & 63];
        part = fmaf(v, v, part);
    }
    for (int off = 32; off; off >>= 1) part += __shfl_down(part, off);
    if ((t & 63) == 0) red[t >> 6] = part;
    __syncthreads();
    if (t == 0)
        s_invtot = 1.f / fmaxf(sqrtf(red[0] + red[1] + red[2] + red[3]), 1e-12f);
    __syncthreads();

    const float invtot = s_invtot;
    float* ob = out + (long)b * (G_ + L_ * M_);
    ob[t] = tokn[b * G_ + t] * invtot;
    for (int idx = t; idx < L_ * M_; idx += 256)
        ob[G_ + idx] = ar[idx] * invm[idx & 63] * invtot;
}

// ---------------------------------------------------------------------------
extern "C" void kernel_launch(void* const* d_in, const int* in_sizes, int n_in,
                              void* d_out, int out_size, void* d_ws, size_t ws_size,
                              hipStream_t stream)
{
    const float* x    = (const float*)d_in[0];
    const float* t_in = (const float*)d_in[1];
    const float* Wt1  = (const float*)d_in[2];
    const float* bt1  = (const float*)d_in[3];
    const float* Wt2  = (const float*)d_in[4];
    const float* bt2  = (const float*)d_in[5];
    const float* Wc1  = (const float*)d_in[6];
    const float* bc1  = (const float*)d_in[7];
    const float* Wc2  = (const float*)d_in[8];
    const float* bc2  = (const float*)d_in[9];
    const float* Ws1  = (const float*)d_in[10];
    const float* bs1  = (const float*)d_in[11];
    const float* Ws2  = (const float*)d_in[12];
    const float* bs2  = (const float*)d_in[13];
    const float* Wtp  = (const float*)d_in[14];
    const float* btp  = (const float*)d_in[15];
    const float* dust = (const float*)d_in[16];
    const float* bb   = (const float*)d_in[17];
    const float* bp   = (const float*)d_in[18];
    const float* lamd = (const float*)d_in[19];

    char* wsb = (char*)d_ws;
    // xT: 16 batches bf16, dead after gemm1; f/p/fnT/smalls overlay it after.
    unsigned short* xT  = (unsigned short*)wsb;                 // 50,331,648 B
    float* f    = (float*)(wsb + 0);                            //  8,388,608 B
    float* p    = (float*)(wsb + 8388608);                      //  4,194,304 B
    unsigned short* fnT = (unsigned short*)(wsb + 12582912);    //  4,194,304 B
    float* hid  = (float*)(wsb + 16777216);                     //     32,768 B
    float* tok  = (float*)(wsb + 16809984);                     //     16,384 B
    float* tokn = (float*)(wsb + 16826368);                     //     16,384 B
    float* T    = (float*)(wsb + 16842752);                     //     65,536 B
    float* draw = (float*)(wsb + 16908288);                     //     65,536 B
    float* part = (float*)(wsb + 16973824);                     //     32,768 B (written by gemm23, post-xt)
    float* avec = (float*)(wsb + 17563648);                     //      4,160 B
    float* avec2= (float*)(wsb + 17567808);                     //      4,160 B
    unsigned short* hT  = (unsigned short*)(wsb + 50331648);    // 33,554,432 B
    unsigned short* Wbf = (unsigned short*)(wsb + 83886080);    //  3,145,728 B
    unsigned short* W2  = (unsigned short*)(wsb + 87031808);    //    393,216 B
    float* aggp = (float*)(wsb + 87425024);                     //  8,388,608 B
    float* out  = (float*)d_out;

    cast_w_kernel<<<2304, 256, 0, stream>>>(Wc1, Ws1, Wc2, Ws2, Wbf, W2);

    xt_kernel   <<<dim3(16, 24, 16), 256, 0, stream>>>(x, xT);
    gemm1_kernel<<<dim3(4, 4, 16), 512, 0, stream>>>(Wbf, xT, bc1, bs1, hT);
    gemm23_kernel<<<dim3(8, 3, 16), 256, 0, stream>>>(W2, hT, bc2, bs2, f, p, part);

    token1_kernel<<<dim3(128, 16), 256, 0, stream>>>(t_in, Wt1, bt1, hid);
    token2_kernel<<<dim3(64, 16), 256, 0, stream>>>(hid, Wt2, bt2, tok);
    token3_kernel<<<16, 256, 0, stream>>>(tok, tokn);

    // linear-domain Sinkhorn: u1 from gemm23 rowsums, (v1+u2), (v2+u3);
    // final v3 fused into agg
    kvku_kernel<true> <<<dim3(17, 16), 256, 0, stream>>>(p, dust, part, avec2);
    kvku_kernel<false><<<dim3(17, 16), 256, 0, stream>>>(p, dust, avec2, avec);

    tnorm_kernel<<<dim3(16, 16), 256, 0, stream>>>(f, Wtp, btp, fnT, T, draw);
    sim_kernel  <<<dim3(4, 16, 16), 256, 0, stream>>>(fnT, T, bb, draw);
    agg_kernel  <<<dim3(16, 16), 256, 0, stream>>>(f, p, avec, dust, draw, bp, lamd, aggp);
    final_kernel<<<16, 256, 0, stream>>>(tokn, aggp, out);
}

// Round 13
// 369.744 us; speedup vs baseline: 1.0655x; 1.0655x over previous
//
#include <hip/hip_runtime.h>
#include <math.h>

#define B_   16
#define C_   1536
#define N_   1024
#define M_   64
#define L_   128
#define G_   256
#define HID_ 512

typedef __attribute__((ext_vector_type(8))) short short8;
typedef __attribute__((ext_vector_type(4))) float floatx4;

// round-to-nearest-even fp32 -> bf16
__device__ __forceinline__ unsigned short f2bf_rne(float x) {
    unsigned u = __float_as_uint(x);
    unsigned r = u + 0x7fffu + ((u >> 16) & 1u);
    return (unsigned short)(r >> 16);
}
// round-half-up packed pair (cheap, hot path)
__device__ __forceinline__ unsigned pack_bf2(float lo, float hi) {
    unsigned a = __float_as_uint(lo) + 0x8000u;
    unsigned b = __float_as_uint(hi) + 0x8000u;
    return (a >> 16) | (b & 0xffff0000u);
}

__device__ __forceinline__ void gl2lds16(const void* g, void* l) {
    __builtin_amdgcn_global_load_lds(
        (const __attribute__((address_space(1))) void*)g,
        (__attribute__((address_space(3))) void*)l, 16, 0, 0);
}

// ---------------------------------------------------------------------------
// Weight cast: Wbf[1024][1536] = stack(Wc1,Ws1) bf16 (float4 path);
// W2[192][1024] = [Wc2 | 0 ; 0 | Ws2] bf16.
// ---------------------------------------------------------------------------
__global__ __launch_bounds__(256) void cast_w_kernel(
    const float* __restrict__ Wc1, const float* __restrict__ Ws1,
    const float* __restrict__ Wc2, const float* __restrict__ Ws2,
    unsigned short* __restrict__ Wbf, unsigned short* __restrict__ W2)
{
    const int V1 = 393216;           // (1024*1536)/4 float4s
    const int VH = 196608;           // Wc1 half in float4s
    int idx = blockIdx.x * 256 + threadIdx.x;
    if (idx < V1) {
        const float4* src = (idx < VH) ? (const float4*)Wc1 : (const float4*)Ws1;
        float4 v = src[(idx < VH) ? idx : idx - VH];
        ushort4 o;
        o.x = f2bf_rne(v.x); o.y = f2bf_rne(v.y);
        o.z = f2bf_rne(v.z); o.w = f2bf_rne(v.w);
        ((ushort4*)Wbf)[idx] = o;
    } else if (idx < V1 + 192 * 1024) {
        int i2 = idx - V1;
        int row = i2 >> 10, k = i2 & 1023;
        float v = 0.f;
        if (row < 128) { if (k < 512) v = Wc2[row * 512 + k]; }
        else           { if (k >= 512) v = Ws2[(row - 128) * 512 + (k - 512)]; }
        W2[i2] = f2bf_rne(v);
    }
}

// ---------------------------------------------------------------------------
// Transpose+cast: xT[b][n][c] bf16 <- x[b][c][n] fp32. 64x64 LDS tile.
// float4 global loads (16B/lane), uint2 global stores (8B/lane).
// ---------------------------------------------------------------------------
__global__ __launch_bounds__(256) void xt_kernel(
    const float* __restrict__ x, unsigned short* __restrict__ xT)
{
    __shared__ float Xs[64][65];
    const int t = threadIdx.x;
    const int n0 = blockIdx.x * 64, c0 = blockIdx.y * 64, b = blockIdx.z;
    const float* xb = x + (long)b * C_ * N_;
    #pragma unroll
    for (int it = 0; it < 4; ++it) {
        int idx = it * 256 + t, cr = idx >> 4, fc = idx & 15;
        float4 v = *(const float4*)&xb[(long)(c0 + cr) * N_ + n0 + fc * 4];
        Xs[cr][fc * 4 + 0] = v.x;
        Xs[cr][fc * 4 + 1] = v.y;
        Xs[cr][fc * 4 + 2] = v.z;
        Xs[cr][fc * 4 + 3] = v.w;
    }
    __syncthreads();
    uint2* xo = (uint2*)(xT + (long)b * N_ * C_);
    #pragma unroll
    for (int it = 0; it < 4; ++it) {
        int idx = it * 256 + t, nr = idx >> 4, pc = idx & 15;
        uint2 o;
        o.x = pack_bf2(Xs[4 * pc + 0][nr], Xs[4 * pc + 1][nr]);
        o.y = pack_bf2(Xs[4 * pc + 2][nr], Xs[4 * pc + 3][nr]);
        xo[(long)(n0 + nr) * 384 + (c0 >> 2) + pc] = o;
    }
}

// ---------------------------------------------------------------------------
// GEMM1 — 256x256-tile 8-phase deep-pipelined bf16 MFMA (m201/HK schedule).
// Direct uint2 C-stores (R12's LDS-transposed epilogue measured -10us: L2
// already merges the 8B stores; the LDS roundtrip was pure overhead).
// ---------------------------------------------------------------------------
#define G1_STAGE_A(kt, q)                                                    \
    gl2lds16(aSrc + (long)(q) * (32 * C_) + (kt) * 64,                       \
             (char*)g1lds + (((kt) & 1) * 65536 + (q) * 8192) + sdst)
#define G1_STAGE_B(kt, q)                                                    \
    gl2lds16(bSrc + (long)(q) * (32 * C_) + (kt) * 64,                       \
             (char*)g1lds + (((kt) & 1) * 65536 + 32768 + (q) * 8192) + sdst)

#define G1_PHASE(q, STAGES, TAIL)                                            \
  {                                                                          \
    const char* ab = cb + aFB + (q) * 8192;                                  \
    short8 a0 = *(const short8*)(ab + ks0);                                  \
    short8 a1 = *(const short8*)(ab + ks1);                                  \
    short8 a2 = *(const short8*)(ab + 2048 + ks0);                           \
    short8 a3 = *(const short8*)(ab + 2048 + ks1);                           \
    STAGES                                                                   \
    __builtin_amdgcn_s_barrier();                                            \
    asm volatile("s_waitcnt lgkmcnt(0)" ::: "memory");                       \
    __builtin_amdgcn_sched_barrier(0);                                       \
    __builtin_amdgcn_s_setprio(1);                                           \
    _Pragma("unroll")                                                        \
    for (int fj = 0; fj < 4; ++fj) {                                         \
      acc[2*(q)][fj]   = __builtin_amdgcn_mfma_f32_16x16x32_bf16(            \
          a0, bfr[fj][0], acc[2*(q)][fj], 0, 0, 0);                          \
      acc[2*(q)][fj]   = __builtin_amdgcn_mfma_f32_16x16x32_bf16(            \
          a1, bfr[fj][1], acc[2*(q)][fj], 0, 0, 0);                          \
      acc[2*(q)+1][fj] = __builtin_amdgcn_mfma_f32_16x16x32_bf16(            \
          a2, bfr[fj][0], acc[2*(q)+1][fj], 0, 0, 0);                        \
      acc[2*(q)+1][fj] = __builtin_amdgcn_mfma_f32_16x16x32_bf16(            \
          a3, bfr[fj][1], acc[2*(q)+1][fj], 0, 0, 0);                        \
    }                                                                        \
    __builtin_amdgcn_s_setprio(0);                                           \
    TAIL                                                                     \
    __builtin_amdgcn_s_barrier();                                            \
    __builtin_amdgcn_sched_barrier(0);                                       \
  }

#define G1_TILE(tt, S1, S2, TAIL3)                                           \
  {                                                                          \
    const char* cb = (const char*)g1lds + ((tt) & 1) * 65536;                \
    _Pragma("unroll")                                                        \
    for (int fj = 0; fj < 4; ++fj) {                                         \
      const char* bb = cb + bFB + (fj >> 1) * 8192 + (fj & 1) * 2048;        \
      bfr[fj][0] = *(const short8*)(bb + ks0);                               \
      bfr[fj][1] = *(const short8*)(bb + ks1);                               \
    }                                                                        \
    G1_PHASE(0, if (S1) { G1_STAGE_A((tt)+1, 2); G1_STAGE_A((tt)+1, 3); }, ) \
    G1_PHASE(1, if (S2) { G1_STAGE_B((tt)+2, 0); G1_STAGE_B((tt)+2, 1); }, ) \
    G1_PHASE(2, if (S2) { G1_STAGE_B((tt)+2, 2); G1_STAGE_B((tt)+2, 3); }, ) \
    G1_PHASE(3, if (S2) { G1_STAGE_A((tt)+2, 0); G1_STAGE_A((tt)+2, 1); }, TAIL3) \
  }

__global__ __launch_bounds__(512, 2) void gemm1_kernel(
    const unsigned short* __restrict__ Wbf, const unsigned short* __restrict__ xT,
    const float* __restrict__ bc1, const float* __restrict__ bs1,
    unsigned short* __restrict__ hT)
{
    __shared__ unsigned short g1lds[65536];   // 128 KiB
    const int t = threadIdx.x;
    const int lane = t & 63, w = t >> 6;
    const int n0 = blockIdx.x * 256, o0 = blockIdx.y * 256, b = blockIdx.z;

    const int sgrow = ((t & 256) ? 128 : 0) + ((t >> 3) & 31);
    const int sdst  = t * 16;
    const int sslot = ((t & 7) ^ ((t >> 3) & 7)) * 8;
    const unsigned short* aSrc = Wbf + (long)(o0 + sgrow) * C_ + sslot;
    const unsigned short* bSrc = xT + (long)b * N_ * C_
                               + (long)(n0 + sgrow) * C_ + sslot;

    const int lrow = lane & 15, kgrp = lane >> 4;
    const int wo = (w >> 2) * 128, wn = (w & 3) * 64;
    const int aFB = (w >> 2) * 4096 + lrow * 128;
    const int bFB = 32768 + ((w >> 1) & 1) * 4096 + (w & 1) * 16384 + lrow * 128;
    const int ks0 = (kgrp ^ (lrow & 7)) * 16;
    const int ks1 = ((4 + kgrp) ^ (lrow & 7)) * 16;

    floatx4 acc[8][4];
    #pragma unroll
    for (int i = 0; i < 8; ++i)
        #pragma unroll
        for (int j = 0; j < 4; ++j) acc[i][j] = (floatx4)0.0f;
    short8 bfr[4][2];

    #pragma unroll
    for (int q = 0; q < 4; ++q) { G1_STAGE_A(0, q); G1_STAGE_B(0, q); }
    #pragma unroll
    for (int q = 0; q < 4; ++q) G1_STAGE_B(1, q);
    G1_STAGE_A(1, 0); G1_STAGE_A(1, 1);
    asm volatile("s_waitcnt vmcnt(6)" ::: "memory");
    __builtin_amdgcn_s_barrier();
    __builtin_amdgcn_sched_barrier(0);

    #pragma unroll 2
    for (int t8 = 0; t8 < 22; ++t8)
        G1_TILE(t8, 1, 1, asm volatile("s_waitcnt vmcnt(6)" ::: "memory");)
    G1_TILE(22, 1, 0, asm volatile("s_waitcnt vmcnt(0)" ::: "memory");)
    G1_TILE(23, 0, 0, )

    const float* bias = (o0 < 512) ? bc1 : bs1;
    const int ob = (o0 < 512) ? o0 : o0 - 512;
    #pragma unroll
    for (int fi = 0; fi < 8; ++fi) {
        const int orow = wo + fi * 16 + kgrp * 4;
        float4 bv = *(const float4*)&bias[ob + orow];
        #pragma unroll
        for (int fj = 0; fj < 4; ++fj) {
            const int n = n0 + wn + fj * 16 + lrow;
            float v0 = fmaxf(acc[fi][fj][0] + bv.x, 0.f);
            float v1 = fmaxf(acc[fi][fj][1] + bv.y, 0.f);
            float v2 = fmaxf(acc[fi][fj][2] + bv.z, 0.f);
            float v3 = fmaxf(acc[fi][fj][3] + bv.w, 0.f);
            uint2 pk;
            pk.x = ((unsigned)f2bf_rne(v0)) | (((unsigned)f2bf_rne(v1)) << 16);
            pk.y = ((unsigned)f2bf_rne(v2)) | (((unsigned)f2bf_rne(v3)) << 16);
            *(uint2*)&hT[((long)b * N_ + n) * 1024 + o0 + orow] = pk;
        }
    }
}

// ---------------------------------------------------------------------------
// GEMM23 (bf16 MFMA): o-blocks 0,1 -> f fp32; o-block 2 -> K = exp(p) fp32
// PLUS deterministic per-(b,nx) partial row sums part[b][nx][64].
// W2 block-diagonal: each o-block runs only its live 512-wide K range.
// ---------------------------------------------------------------------------
__global__ __launch_bounds__(256, 2) void gemm23_kernel(
    const unsigned short* __restrict__ W2, const unsigned short* __restrict__ hT,
    const float* __restrict__ bc2, const float* __restrict__ bs2,
    float* __restrict__ f, float* __restrict__ p, float* __restrict__ part)
{
    __shared__ unsigned short As[64 * 32];
    __shared__ unsigned short Bs[128 * 32];
    __shared__ float prs[M_][2];
    const int t = threadIdx.x;
    const int lane = t & 63, w = t >> 6;
    const int n0 = blockIdx.x * 128, o0 = blockIdx.y * 64, b = blockIdx.z;
    const unsigned short* hTb = hT + (long)b * N_ * 1024;

    const int wo = (w >> 1) * 32, wn = (w & 1) * 64;
    const int lrow = lane & 15, kgrp = lane >> 4;
    const int arow = t >> 2, acol = (t & 3) * 8;
    const int klo = (o0 < 128) ? 0 : 512;   // live K half for this o-block

    floatx4 acc[2][4];
    #pragma unroll
    for (int i = 0; i < 2; ++i)
        #pragma unroll
        for (int j = 0; j < 4; ++j) acc[i][j] = (floatx4)0.0f;

    for (int k0 = 0; k0 < 512; k0 += 32) {
        gl2lds16(W2 + (long)(o0 + arow) * 1024 + klo + k0 + acol, (char*)As + t * 16);
        #pragma unroll
        for (int r = 0; r < 2; ++r)
            gl2lds16(hTb + (long)(n0 + r * 64 + arow) * 1024 + klo + k0 + acol,
                     (char*)Bs + r * 4096 + t * 16);
        __syncthreads();
        short8 af[2], bfr[4];
        #pragma unroll
        for (int i = 0; i < 2; ++i)
            af[i] = *(const short8*)((const char*)As +
                        (wo + i * 16 + lrow) * 64 + kgrp * 16);
        #pragma unroll
        for (int j = 0; j < 4; ++j)
            bfr[j] = *(const short8*)((const char*)Bs +
                        (wn + j * 16 + lrow) * 64 + kgrp * 16);
        #pragma unroll
        for (int i = 0; i < 2; ++i)
            #pragma unroll
            for (int j = 0; j < 4; ++j)
                acc[i][j] = __builtin_amdgcn_mfma_f32_16x16x32_bf16(
                    af[i], bfr[j], acc[i][j], 0, 0, 0);
        __syncthreads();
    }

    if (o0 < 128) {
        #pragma unroll
        for (int i = 0; i < 2; ++i) {
            int o = o0 + wo + i * 16 + kgrp * 4;
            #pragma unroll
            for (int j = 0; j < 4; ++j) {
                int n = n0 + wn + j * 16 + lrow;
                #pragma unroll
                for (int r = 0; r < 4; ++r)
                    f[((long)b * L_ + o + r) * N_ + n] = acc[i][j][r] + bc2[o + r];
            }
        }
    } else {
        float pir[2][4];
        #pragma unroll
        for (int i = 0; i < 2; ++i) {
            const int m = wo + i * 16 + kgrp * 4;   // row within [0,64)
            #pragma unroll
            for (int r = 0; r < 4; ++r) pir[i][r] = 0.f;
            #pragma unroll
            for (int j = 0; j < 4; ++j) {
                int n = n0 + wn + j * 16 + lrow;
                #pragma unroll
                for (int r = 0; r < 4; ++r) {
                    float K = expf(acc[i][j][r] + bs2[m + r]);
                    p[((long)b * M_ + m + r) * N_ + n] = K;
                    pir[i][r] += K;
                }
            }
            #pragma unroll
            for (int r = 0; r < 4; ++r) {
                float s = pir[i][r];
                s += __shfl_xor(s, 1); s += __shfl_xor(s, 2);
                s += __shfl_xor(s, 4); s += __shfl_xor(s, 8);
                if (lrow == 0) prs[m + r][w & 1] = s;
            }
        }
        __syncthreads();
        if (t < M_)
            part[((long)b * 8 + blockIdx.x) * M_ + t] = prs[t][0] + prs[t][1];
    }
}

// ---------------------------------------------------------------------------
// Token head: wave-per-output GEMV kernels (split; wide grids)
// ---------------------------------------------------------------------------
__global__ __launch_bounds__(256) void token1_kernel(
    const float* __restrict__ t_in, const float* __restrict__ Wt1,
    const float* __restrict__ bt1, float* __restrict__ hid)
{
    const int lane = threadIdx.x & 63, w = threadIdx.x >> 6;
    const int o = blockIdx.x * 4 + w, b = blockIdx.y;
    const float4* wr = (const float4*)(Wt1 + (long)o * C_);
    const float4* tb = (const float4*)(t_in + (long)b * C_);
    float acc = 0.f;
    #pragma unroll
    for (int i = 0; i < 6; ++i) {
        float4 a = wr[i * 64 + lane], tv = tb[i * 64 + lane];
        acc += a.x * tv.x + a.y * tv.y + a.z * tv.z + a.w * tv.w;
    }
    #pragma unroll
    for (int off = 1; off < 64; off <<= 1) acc += __shfl_xor(acc, off);
    if (lane == 0) hid[b * HID_ + o] = fmaxf(acc + bt1[o], 0.f);
}

__global__ __launch_bounds__(256) void token2_kernel(
    const float* __restrict__ hid, const float* __restrict__ Wt2,
    const float* __restrict__ bt2, float* __restrict__ tok)
{
    const int lane = threadIdx.x & 63, w = threadIdx.x >> 6;
    const int g = blockIdx.x * 4 + w, b = blockIdx.y;
    const float4* wr = (const float4*)(Wt2 + (long)g * HID_);
    const float4* hb = (const float4*)(hid + (long)b * HID_);
    float acc = 0.f;
    #pragma unroll
    for (int i = 0; i < 2; ++i) {
        float4 a = wr[i * 64 + lane], hv = hb[i * 64 + lane];
        acc += a.x * hv.x + a.y * hv.y + a.z * hv.z + a.w * hv.w;
    }
    #pragma unroll
    for (int off = 1; off < 64; off <<= 1) acc += __shfl_xor(acc, off);
    if (lane == 0) tok[b * G_ + g] = acc + bt2[g];
}

__global__ __launch_bounds__(256) void token3_kernel(
    const float* __restrict__ tok, float* __restrict__ tokn)
{
    __shared__ float red[4];
    const int b = blockIdx.x, t = threadIdx.x;
    float v = tok[b * G_ + t];
    float ss = v * v;
    #pragma unroll
    for (int off = 1; off < 64; off <<= 1) ss += __shfl_xor(ss, off);
    if ((t & 63) == 0) red[t >> 6] = ss;
    __syncthreads();
    float inv = 1.f / fmaxf(sqrtf(red[0] + red[1] + red[2] + red[3]), 1e-12f);
    tokn[b * G_ + t] = v * inv;
}

// ---------------------------------------------------------------------------
// Fused kv+ku pass: each block redundantly computes the full bvec for its
// batch into LDS, then its own row-dots. FIRST variant builds the initial
// a-vector from gemm23's partial row sums (u1) before kv1+ku2.
// ---------------------------------------------------------------------------
template<bool FIRST>
__global__ __launch_bounds__(256) void kvku_kernel(
    const float* __restrict__ K, const float* __restrict__ dust,
    const float* __restrict__ ain, float* __restrict__ avec_out)
{
    __shared__ float a_s[M_ + 1];
    __shared__ float b_lds[N_];
    const int t = threadIdx.x, lane = t & 63, w = t >> 6;
    const int mg = blockIdx.x, b = blockIdx.y;
    const float ea = expf(dust[0]);
    const float* Kb = K + (long)b * M_ * N_;

    if (FIRST) {
        if (t < M_) {
            float s = 0.f;
            #pragma unroll
            for (int nx = 0; nx < 8; ++nx) s += ain[((long)b * 8 + nx) * M_ + t];
            a_s[t] = (1.f / 1088.f) / s;
        } else if (t == M_) {
            a_s[M_] = (1024.f / 1088.f) / (1024.f * ea);
        }
    } else {
        if (t < M_ + 1) a_s[t] = ain[b * (M_ + 1) + t];
    }
    __syncthreads();

    // kv phase, 4 cols/thread
    #pragma unroll
    for (int k = 0; k < 4; ++k) {
        int n = k * 256 + t;
        float s = ea * a_s[M_];
        const float* col = Kb + n;
        #pragma unroll
        for (int m = 0; m < M_; ++m) s = fmaf(col[(long)m * N_], a_s[m], s);
        b_lds[n] = (1.f / 1088.f) / s;
    }
    __syncthreads();

    // ku phase
    const int m = mg * 4 + w;
    if (m > M_) return;
    float s = 0.f;
    if (m < M_) {
        const float* row = Kb + (long)m * N_;
        #pragma unroll
        for (int i = 0; i < 16; ++i) {
            int n = i * 64 + lane;
            s = fmaf(row[n], b_lds[n], s);
        }
    } else {
        #pragma unroll
        for (int i = 0; i < 16; ++i) s += b_lds[i * 64 + lane];
        s *= ea;
    }
    #pragma unroll
    for (int off = 1; off < 64; off <<= 1) s += __shfl_xor(s, off);
    if (lane == 0) {
        float mu = (m < M_) ? (1.f / 1088.f) : (1024.f / 1088.f);
        avec_out[b * (M_ + 1) + m] = mu / s;
    }
}

// ---------------------------------------------------------------------------
// tnorm: computes T, zeroes draw, writes fnT[b][n][128] bf16.
// ---------------------------------------------------------------------------
__global__ __launch_bounds__(256) void tnorm_kernel(
    const float* __restrict__ f, const float* __restrict__ Wtp,
    const float* __restrict__ btp, unsigned short* __restrict__ fnT,
    float* __restrict__ T, float* __restrict__ draw)
{
    __shared__ float Ft[L_][65];
    __shared__ float red_ss[4][64];
    __shared__ float red_dot[4][64];
    __shared__ float invs[64];
    __shared__ float wtp_s[L_];
    const int b = blockIdx.y, n0 = blockIdx.x * 64, t = threadIdx.x;
    const float* fb = f + (long)b * L_ * N_;

    if (t < L_) wtp_s[t] = Wtp[t];
    for (int it = 0; it < 32; ++it) {
        int idx = it * 256 + t;
        int l = idx >> 6, c = idx & 63;
        Ft[l][c] = fb[(long)l * N_ + n0 + c];
    }
    __syncthreads();
    {
        const int lg = t >> 6, col = t & 63;
        float ss = 0.f, dot = 0.f;
        #pragma unroll
        for (int i = 0; i < 32; ++i) {
            int l = lg * 32 + i;
            float v = Ft[l][col];
            ss = fmaf(v, v, ss);
            dot = fmaf(v, wtp_s[l], dot);
        }
        red_ss[lg][col] = ss;
        red_dot[lg][col] = dot;
    }
    __syncthreads();
    if (t < 64) {
        float ss = ((red_ss[0][t] + red_ss[1][t]) + (red_ss[2][t] + red_ss[3][t]));
        float dot = ((red_dot[0][t] + red_dot[1][t]) + (red_dot[2][t] + red_dot[3][t]));
        invs[t] = 1.f / fmaxf(sqrtf(ss), 1e-12f);
        float xx = dot + btp[0];
        T[b * N_ + n0 + t] = (xx > 0.f) ? (xx + log1pf(expf(-xx)))
                                        : log1pf(expf(xx));
        draw[b * N_ + n0 + t] = 0.f;
    }
    __syncthreads();
    unsigned* fo = (unsigned*)fnT;
    for (int it = 0; it < 16; ++it) {
        int idx = it * 256 + t;
        int nl = idx >> 6, jp = idx & 63;
        float inv = invs[nl];
        fo[(((long)b * N_ + n0 + nl) << 6) + jp] =
            pack_bf2(Ft[2 * jp][nl] * inv, Ft[2 * jp + 1][nl] * inv);
    }
}

// ---------------------------------------------------------------------------
// sim (bf16 MFMA): draw[b][i] += sum_j sigmoid(0.5*(Ti+Tj)*(fn_i . fn_j) + bb)
// ---------------------------------------------------------------------------
__global__ __launch_bounds__(256) void sim_kernel(
    const unsigned short* __restrict__ fnT, const float* __restrict__ T,
    const float* __restrict__ bb, float* __restrict__ draw)
{
    __shared__ unsigned short As[64 * 136];
    __shared__ unsigned short Bs[64 * 136];
    __shared__ float Ti[64], Tj[64];
    const int b = blockIdx.z, i0 = blockIdx.y * 64, j0base = blockIdx.x * 256;
    const int t = threadIdx.x, lane = t & 63, w = t >> 6;
    const int lrow = lane & 15, kgrp = lane >> 4;
    const unsigned short* fb = fnT + (long)b * N_ * 128;
    const float burstb = bb[0];

    if (t < 64) Ti[t] = T[b * N_ + i0 + t];
    const int srow = t >> 4, scol = (t & 15) * 8;
    #pragma unroll
    for (int r = 0; r < 4; ++r) {
        uint4 av = *(const uint4*)(fb + (long)(i0 + r * 16 + srow) * 128 + scol);
        *(uint4*)((char*)As + (r * 16 + srow) * 272 + scol * 2) = av;
    }
    uint4 bv[4];
    #pragma unroll
    for (int r = 0; r < 4; ++r)
        bv[r] = *(const uint4*)(fb + (long)(j0base + r * 16 + srow) * 128 + scol);

    float rs[4] = {0.f, 0.f, 0.f, 0.f};
    #pragma unroll
    for (int jj = 0; jj < 4; ++jj) {
        __syncthreads();
        #pragma unroll
        for (int r = 0; r < 4; ++r)
            *(uint4*)((char*)Bs + (r * 16 + srow) * 272 + scol * 2) = bv[r];
        if (t >= 64 && t < 128) Tj[t - 64] = T[b * N_ + j0base + jj * 64 + (t - 64)];
        if (jj < 3) {
            #pragma unroll
            for (int r = 0; r < 4; ++r)
                bv[r] = *(const uint4*)(fb +
                    (long)(j0base + (jj + 1) * 64 + r * 16 + srow) * 128 + scol);
        }
        __syncthreads();

        floatx4 acc[4];
        #pragma unroll
        for (int j = 0; j < 4; ++j) acc[j] = (floatx4)0.0f;
        __builtin_amdgcn_s_setprio(1);
        #pragma unroll
        for (int k0 = 0; k0 < 128; k0 += 32) {
            short8 af = *(const short8*)((const char*)As +
                            (w * 16 + lrow) * 272 + k0 * 2 + kgrp * 16);
            #pragma unroll
            for (int j = 0; j < 4; ++j) {
                short8 bf = *(const short8*)((const char*)Bs +
                                (j * 16 + lrow) * 272 + k0 * 2 + kgrp * 16);
                acc[j] = __builtin_amdgcn_mfma_f32_16x16x32_bf16(af, bf, acc[j], 0, 0, 0);
            }
        }
        __builtin_amdgcn_s_setprio(0);
        #pragma unroll
        for (int j = 0; j < 4; ++j) {
            float Tjv = Tj[j * 16 + lrow];
            #pragma unroll
            for (int r = 0; r < 4; ++r) {
                float Tiv = Ti[w * 16 + kgrp * 4 + r];
                float xarg = 0.5f * (Tiv + Tjv) * acc[j][r] + burstb;
                rs[r] += 1.f / (1.f + expf(-xarg));
            }
        }
    }

    #pragma unroll
    for (int off = 1; off < 16; off <<= 1)
        #pragma unroll
        for (int r = 0; r < 4; ++r) rs[r] += __shfl_xor(rs[r], off);
    if (lrow == 0) {
        #pragma unroll
        for (int r = 0; r < 4; ++r)
            atomicAdd(&draw[b * N_ + i0 + w * 16 + kgrp * 4 + r], rs[r]);
    }
}

// ---------------------------------------------------------------------------
// agg (+ fused final kv + inlined wn): Pch[m][c] = K[m][n0+c]*a[m];
// s_c = sum_m Pch + dust; cf[c] = wn(draw[c])/s_c. ATOMIC-FREE: block
// (nb,b) writes its private L x M slice to aggp[b][nb][L*M].
// ---------------------------------------------------------------------------
__global__ __launch_bounds__(256) void agg_kernel(
    const float* __restrict__ f, const float* __restrict__ Kmat,
    const float* __restrict__ avec, const float* __restrict__ dust,
    const float* __restrict__ draw, const float* __restrict__ bp,
    const float* __restrict__ lamd, float* __restrict__ aggp)
{
    __shared__ float fch[L_][65];
    __shared__ float Pch[M_][65];
    __shared__ float a_s[M_ + 1], cf[64];
    const int b = blockIdx.y, nb = blockIdx.x, n0 = nb * 64;
    const int t = threadIdx.x, tx = t & 15, ty = t >> 4;
    const float* fb = f + (long)b * L_ * N_;
    const float* Kb = Kmat + (long)b * M_ * N_;

    if (t < M_ + 1) a_s[t] = avec[b * (M_ + 1) + t];
    __syncthreads();

    for (int idx = t; idx < L_ * 64; idx += 256) {
        int l = idx >> 6, c = idx & 63;
        fch[l][c] = fb[(long)l * N_ + n0 + c];
    }
    for (int idx = t; idx < M_ * 64; idx += 256) {
        int m = idx >> 6, c = idx & 63;
        Pch[m][c] = Kb[(long)m * N_ + n0 + c] * a_s[m];
    }
    __syncthreads();

    if (t < 64) {
        float s = expf(dust[0]) * a_s[M_];
        #pragma unroll
        for (int m = 0; m < M_; ++m) s += Pch[m][t];
        float d = powf(draw[b * N_ + n0 + t], bp[0]);
        d = fminf(fmaxf(d, 1e-3f), 1e3f);
        float lam = 1.f / (1.f + expf(-lamd[0]));
        cf[t] = ((1.f - lam) + lam / (d + 1e-6f)) / s;
    }
    __syncthreads();

    float acc[8][4] = {};
    for (int n = 0; n < 64; ++n) {
        float cfn = cf[n];
        float fv[8], pv[4];
        #pragma unroll
        for (int i = 0; i < 8; ++i) fv[i] = fch[ty + 16 * i][n];
        #pragma unroll
        for (int j = 0; j < 4; ++j) pv[j] = Pch[tx * 4 + j][n] * cfn;
        #pragma unroll
        for (int i = 0; i < 8; ++i)
            #pragma unroll
            for (int j = 0; j < 4; ++j)
                acc[i][j] = fmaf(fv[i], pv[j], acc[i][j]);
    }
    float* op = aggp + ((long)b * 16 + nb) * (L_ * M_);
    #pragma unroll
    for (int i = 0; i < 8; ++i) {
        float4 v = make_float4(acc[i][0], acc[i][1], acc[i][2], acc[i][3]);
        *(float4*)&op[(ty + 16 * i) * M_ + tx * 4] = v;
    }
}

// ---------------------------------------------------------------------------
// final: reduce 16 agg slices -> LDS, per-cluster l2norm over L,
// concat [tok_n, agg_n], global l2norm.
// ---------------------------------------------------------------------------
__global__ __launch_bounds__(256) void final_kernel(
    const float* __restrict__ tokn, const float* __restrict__ aggp,
    float* __restrict__ out)
{
    __shared__ float ar[L_ * M_];    // 32 KiB
    __shared__ float invm[M_];
    __shared__ float red[4];
    __shared__ float s_invtot;
    const int b = blockIdx.x, t = threadIdx.x;
    const float* pb = aggp + (long)b * 16 * (L_ * M_);

    for (int idx = t; idx < L_ * M_; idx += 256) {
        float s = 0.f;
        #pragma unroll
        for (int nb = 0; nb < 16; ++nb) s += pb[nb * (L_ * M_) + idx];
        ar[idx] = s;
    }
    __syncthreads();

    if (t < 64) {
        float ss = 0.f;
        for (int l = 0; l < L_; ++l) {
            float v = ar[l * M_ + t];
            ss = fmaf(v, v, ss);
        }
        invm[t] = 1.f / fmaxf(sqrtf(ss), 1e-12f);
    }
    __syncthreads();

    float part;
    {
        float tn = tokn[b * G_ + t];
        part = tn * tn;
    }
    for (int idx = t; idx < L_ * M_; idx += 256) {
        float v = ar[idx] * invm[idx & 63];
        part = fmaf(v, v, part);
    }
    for (int off = 32; off; off >>= 1) part += __shfl_down(part, off);
    if ((t & 63) == 0) red[t >> 6] = part;
    __syncthreads();
    if (t == 0)
        s_invtot = 1.f / fmaxf(sqrtf(red[0] + red[1] + red[2] + red[3]), 1e-12f);
    __syncthreads();

    const float invtot = s_invtot;
    float* ob = out + (long)b * (G_ + L_ * M_);
    ob[t] = tokn[b * G_ + t] * invtot;
    for (int idx = t; idx < L_ * M_; idx += 256)
        ob[G_ + idx] = ar[idx] * invm[idx & 63] * invtot;
}

// ---------------------------------------------------------------------------
extern "C" void kernel_launch(void* const* d_in, const int* in_sizes, int n_in,
                              void* d_out, int out_size, void* d_ws, size_t ws_size,
                              hipStream_t stream)
{
    const float* x    = (const float*)d_in[0];
    const float* t_in = (const float*)d_in[1];
    const float* Wt1  = (const float*)d_in[2];
    const float* bt1  = (const float*)d_in[3];
    const float* Wt2  = (const float*)d_in[4];
    const float* bt2  = (const float*)d_in[5];
    const float* Wc1  = (const float*)d_in[6];
    const float* bc1  = (const float*)d_in[7];
    const float* Wc2  = (const float*)d_in[8];
    const float* bc2  = (const float*)d_in[9];
    const float* Ws1  = (const float*)d_in[10];
    const float* bs1  = (const float*)d_in[11];
    const float* Ws2  = (const float*)d_in[12];
    const float* bs2  = (const float*)d_in[13];
    const float* Wtp  = (const float*)d_in[14];
    const float* btp  = (const float*)d_in[15];
    const float* dust = (const float*)d_in[16];
    const float* bb   = (const float*)d_in[17];
    const float* bp   = (const float*)d_in[18];
    const float* lamd = (const float*)d_in[19];

    char* wsb = (char*)d_ws;
    // xT: 16 batches bf16, dead after gemm1; f/p/fnT/smalls overlay it after.
    unsigned short* xT  = (unsigned short*)wsb;                 // 50,331,648 B
    float* f    = (float*)(wsb + 0);                            //  8,388,608 B
    float* p    = (float*)(wsb + 8388608);                      //  4,194,304 B
    unsigned short* fnT = (unsigned short*)(wsb + 12582912);    //  4,194,304 B
    float* hid  = (float*)(wsb + 16777216);                     //     32,768 B
    float* tok  = (float*)(wsb + 16809984);                     //     16,384 B
    float* tokn = (float*)(wsb + 16826368);                     //     16,384 B
    float* T    = (float*)(wsb + 16842752);                     //     65,536 B
    float* draw = (float*)(wsb + 16908288);                     //     65,536 B
    float* part = (float*)(wsb + 16973824);                     //     32,768 B (written by gemm23, post-xt)
    float* avec = (float*)(wsb + 17563648);                     //      4,160 B
    float* avec2= (float*)(wsb + 17567808);                     //      4,160 B
    unsigned short* hT  = (unsigned short*)(wsb + 50331648);    // 33,554,432 B
    unsigned short* Wbf = (unsigned short*)(wsb + 83886080);    //  3,145,728 B
    unsigned short* W2  = (unsigned short*)(wsb + 87031808);    //    393,216 B
    float* aggp = (float*)(wsb + 87425024);                     //  8,388,608 B
    float* out  = (float*)d_out;

    cast_w_kernel<<<2304, 256, 0, stream>>>(Wc1, Ws1, Wc2, Ws2, Wbf, W2);

    xt_kernel   <<<dim3(16, 24, 16), 256, 0, stream>>>(x, xT);
    gemm1_kernel<<<dim3(4, 4, 16), 512, 0, stream>>>(Wbf, xT, bc1, bs1, hT);
    gemm23_kernel<<<dim3(8, 3, 16), 256, 0, stream>>>(W2, hT, bc2, bs2, f, p, part);

    token1_kernel<<<dim3(128, 16), 256, 0, stream>>>(t_in, Wt1, bt1, hid);
    token2_kernel<<<dim3(64, 16), 256, 0, stream>>>(hid, Wt2, bt2, tok);
    token3_kernel<<<16, 256, 0, stream>>>(tok, tokn);

    // linear-domain Sinkhorn: u1 from gemm23 rowsums, (v1+u2), (v2+u3);
    // final v3 fused into agg
    kvku_kernel<true> <<<dim3(17, 16), 256, 0, stream>>>(p, dust, part, avec2);
    kvku_kernel<false><<<dim3(17, 16), 256, 0, stream>>>(p, dust, avec2, avec);

    tnorm_kernel<<<dim3(16, 16), 256, 0, stream>>>(f, Wtp, btp, fnT, T, draw);
    sim_kernel  <<<dim3(4, 16, 16), 256, 0, stream>>>(fnT, T, bb, draw);
    agg_kernel  <<<dim3(16, 16), 256, 0, stream>>>(f, p, avec, dust, draw, bp, lamd, aggp);
    final_kernel<<<16, 256, 0, stream>>>(tokn, aggp, out);
}